// Round 1
// baseline (2233.327 us; speedup 1.0000x reference)
//
#include <hip/hip_runtime.h>
#include <hip/hip_bf16.h>

typedef __hip_bfloat16 bf16;

#define DEV __device__ __forceinline__

DEV float toF(float x) { return x; }
DEV float toF(bf16 x) { return __bfloat162float(x); }
DEV void storeF(float* p, float v) { *p = v; }
DEV void storeF(bf16* p, float v) { *p = __float2bfloat16(v); }

// monotone float <-> uint mapping for atomicMax on floats (handles negatives)
DEV unsigned fenc(float f) {
    unsigned u = __float_as_uint(f);
    return (u & 0x80000000u) ? ~u : (u | 0x80000000u);
}
DEV float fdec(unsigned u) {
    unsigned b = (u & 0x80000000u) ? (u & 0x7FFFFFFFu) : ~u;
    return __uint_as_float(b);
}

DEV float waveReduceSum(float v) {
    #pragma unroll
    for (int m = 1; m < 64; m <<= 1) v += __shfl_xor(v, m);
    return v;
}

// ---------------- encoders ----------------
__global__ __launch_bounds__(256) void node_enc_k(
    const float* __restrict__ x, const float* __restrict__ w,
    const float* __restrict__ b, float* __restrict__ h, int N) {
    int t = blockIdx.x * 256 + threadIdx.x;
    if (t >= N * 128) return;
    int n = t >> 7, d = t & 127;
    float acc = b[d];
    #pragma unroll
    for (int i = 0; i < 9; ++i) acc += x[n * 9 + i] * w[i * 128 + d];
    h[t] = fmaxf(acc, 0.f);
}

__global__ __launch_bounds__(256) void edge_enc_k(
    const float* __restrict__ ea, const float* __restrict__ w,
    const float* __restrict__ b, bf16* __restrict__ out, int E) {
    int t = blockIdx.x * 256 + threadIdx.x;
    if (t >= E * 128) return;
    int e = t >> 7, d = t & 127;
    float acc = b[d];
    #pragma unroll
    for (int i = 0; i < 3; ++i) acc += ea[e * 3 + i] * w[i * 128 + d];
    out[t] = __float2bfloat16(acc);
}

// ---------------- generic [M,128] @ [128,128] (+bias) ----------------
template <typename TIN, typename TOUT, bool BIAS>
__global__ __launch_bounds__(256) void gemm128(
    const TIN* __restrict__ A, const float* __restrict__ W,
    const float* __restrict__ bias, TOUT* __restrict__ outp, int M) {
    __shared__ float As[64][128];
    int tid = threadIdx.x;
    int row0 = blockIdx.x * 64;
    for (int i = tid; i < 64 * 128; i += 256) {
        int r = i >> 7, c = i & 127;
        int gr = row0 + r;
        As[r][c] = (gr < M) ? toF(A[(size_t)gr * 128 + c]) : 0.f;
    }
    __syncthreads();
    int tx = tid & 31, ty = tid >> 5;
    float acc[8][4] = {};
    for (int k = 0; k < 128; ++k) {
        float4 w4 = *(const float4*)(W + k * 128 + tx * 4);
        #pragma unroll
        for (int rr = 0; rr < 8; ++rr) {
            float a = As[ty * 8 + rr][k];
            acc[rr][0] += a * w4.x;
            acc[rr][1] += a * w4.y;
            acc[rr][2] += a * w4.z;
            acc[rr][3] += a * w4.w;
        }
    }
    #pragma unroll
    for (int rr = 0; rr < 8; ++rr) {
        int gr = row0 + ty * 8 + rr;
        if (gr >= M) continue;
        #pragma unroll
        for (int jj = 0; jj < 4; ++jj) {
            int col = tx * 4 + jj;
            float v = acc[rr][jj];
            if (BIAS) v += bias[col];
            storeF(&outp[(size_t)gr * 128 + col], v);
        }
    }
}

// ---------------- edge attention ----------------
// alpha_raw per (edge, head); atomicMax running max per (dst, head)
__global__ __launch_bounds__(256) void alpha_k(
    const int* __restrict__ ei, const float* __restrict__ Q,
    const float* __restrict__ K, const bf16* __restrict__ e_,
    float* __restrict__ alpha, unsigned* __restrict__ m_u, int E) {
    int t = blockIdx.x * 256 + threadIdx.x;
    int edge = t >> 7;
    if (edge >= E) return;
    int d = t & 127;
    int src = ei[edge], dst = ei[E + edge];
    float q = Q[(size_t)dst * 128 + d];
    float ke = K[(size_t)src * 128 + d] + __bfloat162float(e_[(size_t)edge * 128 + d]);
    float p = q * ke;
    p += __shfl_xor(p, 1);
    p += __shfl_xor(p, 2);
    p += __shfl_xor(p, 4);
    p += __shfl_xor(p, 8);
    if ((d & 15) == 0) {
        int hh = d >> 4;
        float a = p * 0.25f;  // / sqrt(16)
        alpha[edge * 8 + hh] = a;
        atomicMax(&m_u[dst * 8 + hh], fenc(a));
    }
}

__global__ __launch_bounds__(256) void expden_k(
    const int* __restrict__ ei, float* __restrict__ alpha,
    const unsigned* __restrict__ m_u, float* __restrict__ denom, int E) {
    int t = blockIdx.x * 256 + threadIdx.x;
    if (t >= E * 8) return;
    int edge = t >> 3, hh = t & 7;
    int dst = ei[E + edge];
    float a = __expf(alpha[t] - fdec(m_u[dst * 8 + hh]));
    alpha[t] = a;
    atomicAdd(&denom[dst * 8 + hh], a);
}

__global__ __launch_bounds__(256) void scatter_k(
    const int* __restrict__ ei, const float* __restrict__ V,
    const bf16* __restrict__ e_, const float* __restrict__ alpha,
    const float* __restrict__ denom, float* __restrict__ out_agg, int E) {
    int t = blockIdx.x * 256 + threadIdx.x;
    int edge = t >> 7;
    if (edge >= E) return;
    int d = t & 127, hh = d >> 4;
    int src = ei[edge], dst = ei[E + edge];
    float w = alpha[edge * 8 + hh] / (denom[dst * 8 + hh] + 1e-16f);
    float msg = (V[(size_t)src * 128 + d] + __bfloat162float(e_[(size_t)edge * 128 + d])) * w;
    atomicAdd(&out_agg[(size_t)dst * 128 + d], msg);
}

// ---------------- beta gate + residual + layernorm (one wave per node) ----------------
__global__ __launch_bounds__(64) void combine_k(
    const float* __restrict__ out_agg, const float* __restrict__ S,
    float* __restrict__ h, const float* __restrict__ Wb,
    const float* __restrict__ lng, const float* __restrict__ lnb, int N) {
    int n = blockIdx.x;
    int t = threadIdx.x;
    int d0 = t, d1 = t + 64;
    size_t base = (size_t)n * 128;
    float o0 = out_agg[base + d0], o1 = out_agg[base + d1];
    float s0 = S[base + d0], s1 = S[base + d1];
    float part = o0 * Wb[d0] + s0 * Wb[128 + d0] + (o0 - s0) * Wb[256 + d0]
               + o1 * Wb[d1] + s1 * Wb[128 + d1] + (o1 - s1) * Wb[256 + d1];
    float g = waveReduceSum(part);
    float beta = 1.f / (1.f + __expf(-g));
    float y0 = beta * s0 + (1.f - beta) * o0;
    float y1 = beta * s1 + (1.f - beta) * o1;
    float z0 = y0 + h[base + d0];
    float z1 = y1 + h[base + d1];
    float mean = waveReduceSum(z0 + z1) * (1.f / 128.f);
    float c0 = z0 - mean, c1 = z1 - mean;
    float var = waveReduceSum(c0 * c0 + c1 * c1) * (1.f / 128.f);
    float inv = rsqrtf(var + 1e-5f);
    h[base + d0] = c0 * inv * lng[d0] + lnb[d0];
    h[base + d1] = c1 * inv * lng[d1] + lnb[d1];
}

// ---------------- pooling + head ----------------
__global__ __launch_bounds__(256) void pool_sum_k(
    const float* __restrict__ h, const int* __restrict__ batch,
    float* __restrict__ psum, int N) {
    int t = blockIdx.x * 256 + threadIdx.x;
    if (t >= N * 128) return;
    int n = t >> 7, d = t & 127;
    atomicAdd(&psum[batch[n] * 128 + d], h[t]);
}

__global__ __launch_bounds__(256) void pool_cnt_k(
    const int* __restrict__ batch, float* __restrict__ pcnt, int N) {
    int t = blockIdx.x * 256 + threadIdx.x;
    if (t >= N) return;
    atomicAdd(&pcnt[batch[t]], 1.f);
}

__global__ __launch_bounds__(64) void head_k(
    const float* __restrict__ psum, const float* __restrict__ pcnt,
    const float* __restrict__ h1w, const float* __restrict__ h1b,
    const float* __restrict__ h2w, const float* __restrict__ h2b,
    float* __restrict__ out) {
    __shared__ float pl[128];
    __shared__ float hid[64];
    int g = blockIdx.x;
    int t = threadIdx.x;
    float cnt = fmaxf(pcnt[g], 1.f);
    for (int i = t; i < 128; i += 64) pl[i] = psum[g * 128 + i] / cnt;
    __syncthreads();
    float a = h1b[t];
    for (int k = 0; k < 128; ++k) a += pl[k] * h1w[k * 64 + t];
    hid[t] = fmaxf(a, 0.f);
    __syncthreads();
    if (t < 10) {
        float o = h2b[t];
        for (int k = 0; k < 64; ++k) o += hid[k] * h2w[k * 10 + t];
        out[g * 10 + t] = o;
    }
}

extern "C" void kernel_launch(void* const* d_in, const int* in_sizes, int n_in,
                              void* d_out, int out_size, void* d_ws, size_t ws_size,
                              hipStream_t stream) {
    const float* x      = (const float*)d_in[0];
    const int*   ei     = (const int*)d_in[1];
    const float* eattr  = (const float*)d_in[2];
    const int*   batch  = (const int*)d_in[3];
    const float* node_w = (const float*)d_in[4];
    const float* node_b = (const float*)d_in[5];
    const float* edge_w = (const float*)d_in[6];
    const float* edge_b = (const float*)d_in[7];
    const float* Wq     = (const float*)d_in[8];
    const float* bq     = (const float*)d_in[9];
    const float* Wk     = (const float*)d_in[10];
    const float* bk     = (const float*)d_in[11];
    const float* Wv     = (const float*)d_in[12];
    const float* bv     = (const float*)d_in[13];
    const float* We     = (const float*)d_in[14];
    const float* Wskip  = (const float*)d_in[15];
    const float* bskip  = (const float*)d_in[16];
    const float* Wbeta  = (const float*)d_in[17];
    const float* ln_g   = (const float*)d_in[18];
    const float* ln_b   = (const float*)d_in[19];
    const float* h1_w   = (const float*)d_in[20];
    const float* h1_b   = (const float*)d_in[21];
    const float* h2_w   = (const float*)d_in[22];
    const float* h2_b   = (const float*)d_in[23];
    float* out = (float*)d_out;

    const int N = in_sizes[3];
    const int E = in_sizes[2] / 3;
    const int G = 128;
    const int L = 4;

    // workspace layout
    char* w = (char*)d_ws;
    auto alloc = [&](size_t bytes) {
        char* p = w;
        w += (bytes + 255) & ~(size_t)255;
        return p;
    };
    float* h       = (float*)alloc((size_t)N * 128 * 4);
    float* Q       = (float*)alloc((size_t)N * 128 * 4);
    float* K       = (float*)alloc((size_t)N * 128 * 4);
    float* V       = (float*)alloc((size_t)N * 128 * 4);
    float* S       = (float*)alloc((size_t)N * 128 * 4);
    bf16*  ea      = (bf16*)alloc((size_t)E * 128 * 2);
    bf16*  e_      = (bf16*)alloc((size_t)E * 128 * 2);
    float* alphaB  = (float*)alloc((size_t)E * 8 * 4);
    unsigned* m_u  = (unsigned*)alloc((size_t)N * 8 * 4);
    float* denom   = (float*)alloc((size_t)N * 8 * 4);
    float* out_agg = (float*)alloc((size_t)N * 128 * 4);
    float* psum    = (float*)alloc((size_t)G * 128 * 4);
    float* pcnt    = (float*)alloc((size_t)G * 4);

    dim3 b256(256), b64(64);

    // encoders
    node_enc_k<<<(N * 128 + 255) / 256, b256, 0, stream>>>(x, node_w, node_b, h, N);
    edge_enc_k<<<(E * 128 + 255) / 256, b256, 0, stream>>>(eattr, edge_w, edge_b, ea, E);

    int gN = (N + 63) / 64, gE = (E + 63) / 64;
    for (int l = 0; l < L; ++l) {
        const float* Wq_l = Wq + (size_t)l * 128 * 128;
        const float* Wk_l = Wk + (size_t)l * 128 * 128;
        const float* Wv_l = Wv + (size_t)l * 128 * 128;
        const float* We_l = We + (size_t)l * 128 * 128;
        const float* Ws_l = Wskip + (size_t)l * 128 * 128;

        gemm128<float, float, true><<<gN, b256, 0, stream>>>(h, Wq_l, bq + l * 128, Q, N);
        gemm128<float, float, true><<<gN, b256, 0, stream>>>(h, Wk_l, bk + l * 128, K, N);
        gemm128<float, float, true><<<gN, b256, 0, stream>>>(h, Wv_l, bv + l * 128, V, N);
        gemm128<float, float, true><<<gN, b256, 0, stream>>>(h, Ws_l, bskip + l * 128, S, N);
        gemm128<bf16, bf16, false><<<gE, b256, 0, stream>>>(ea, We_l, nullptr, e_, E);

        hipMemsetAsync(m_u, 0, (size_t)N * 8 * 4, stream);
        hipMemsetAsync(denom, 0, (size_t)N * 8 * 4, stream);
        hipMemsetAsync(out_agg, 0, (size_t)N * 128 * 4, stream);

        alpha_k<<<(E * 128 + 255) / 256, b256, 0, stream>>>(ei, Q, K, e_, alphaB, m_u, E);
        expden_k<<<(E * 8 + 255) / 256, b256, 0, stream>>>(ei, alphaB, m_u, denom, E);
        scatter_k<<<(E * 128 + 255) / 256, b256, 0, stream>>>(ei, V, e_, alphaB, denom, out_agg, E);

        combine_k<<<N, b64, 0, stream>>>(out_agg, S, h, Wbeta + (size_t)l * 384,
                                         ln_g + (size_t)l * 128, ln_b + (size_t)l * 128, N);
    }

    hipMemsetAsync(psum, 0, (size_t)G * 128 * 4, stream);
    hipMemsetAsync(pcnt, 0, (size_t)G * 4, stream);
    pool_sum_k<<<(N * 128 + 255) / 256, b256, 0, stream>>>(h, batch, psum, N);
    pool_cnt_k<<<(N + 255) / 256, b256, 0, stream>>>(batch, pcnt, N);
    head_k<<<G, b64, 0, stream>>>(psum, pcnt, h1_w, h1_b, h2_w, h2_b, out);
}

// Round 2
// 754.765 us; speedup vs baseline: 2.9590x; 2.9590x over previous
//
#include <hip/hip_runtime.h>
#include <hip/hip_bf16.h>

typedef __hip_bfloat16 bf16;
typedef __attribute__((ext_vector_type(8))) short short8;
typedef __attribute__((ext_vector_type(4))) float f32x4;

#define DEV __device__ __forceinline__

DEV float blo(unsigned u) { return __uint_as_float(u << 16); }
DEV float bhi(unsigned u) { return __uint_as_float(u & 0xffff0000u); }

DEV float waveReduceSum(float v) {
#pragma unroll
    for (int m = 1; m < 64; m <<= 1) v += __shfl_xor(v, m);
    return v;
}

// ---------------- weight packing into MFMA B-fragment order ----------------
// B frag for 16x16x32: lane l supplies B[k][n] with k=(l>>4)*8+j (j=0..7), n=l&15,
// over kb (K/32) and nb (N/16) blocks. packed idx = ((nb*4+kb)*64+l)*8+j.
__global__ __launch_bounds__(256) void pack_w_k(
    const float* __restrict__ Wq, const float* __restrict__ Wk,
    const float* __restrict__ Wv, const float* __restrict__ Ws,
    const float* __restrict__ We, bf16* __restrict__ outp, int L) {
    int t = blockIdx.x * 256 + threadIdx.x;
    if (t >= 5 * L * 16384) return;
    int p = t & 16383;
    int ls = t >> 14;
    int l = ls / 5, s = ls % 5;
    int j = p & 7, ln = (p >> 3) & 63, kb = (p >> 9) & 3, nb = p >> 11;
    int k = kb * 32 + (ln >> 4) * 8 + j;
    int n = nb * 16 + (ln & 15);
    const float* W = (s == 0) ? Wq : (s == 1) ? Wk : (s == 2) ? Wv : (s == 3) ? Ws : We;
    outp[t] = __float2bfloat16(W[(size_t)l * 16384 + k * 128 + n]);
}

__global__ __launch_bounds__(256) void pack_b_k(
    const float* __restrict__ bq, const float* __restrict__ bk,
    const float* __restrict__ bv, const float* __restrict__ bs,
    float* __restrict__ outp, int L) {
    int t = blockIdx.x * 256 + threadIdx.x;
    if (t >= 4 * L * 128) return;
    int d = t & 127;
    int ls = t >> 7;
    int l = ls >> 2, s = ls & 3;
    const float* B = (s == 0) ? bq : (s == 1) ? bk : (s == 2) ? bv : bs;
    outp[t] = B[l * 128 + d];
}

// ---------------- CSR build ----------------
__global__ __launch_bounds__(256) void hist_k(const int* __restrict__ ei,
                                              int* __restrict__ deg, int E) {
    int e = blockIdx.x * 256 + threadIdx.x;
    if (e >= E) return;
    atomicAdd(&deg[ei[E + e]], 1);
}

__global__ __launch_bounds__(1024) void scan_k(const int* __restrict__ deg,
                                               int* __restrict__ off,
                                               int* __restrict__ cursor, int N, int E) {
    __shared__ int part[1024];
    int t = threadIdx.x;
    int chunk = (N + 1023) >> 10;
    int lo = t * chunk, hi = min(lo + chunk, N);
    int s = 0;
    for (int i = lo; i < hi; ++i) s += deg[i];
    part[t] = s;
    __syncthreads();
    for (int d = 1; d < 1024; d <<= 1) {
        int v = (t >= d) ? part[t - d] : 0;
        __syncthreads();
        part[t] += v;
        __syncthreads();
    }
    int base = (t == 0) ? 0 : part[t - 1];
    for (int i = lo; i < hi; ++i) {
        off[i] = base;
        cursor[i] = base;
        base += deg[i];
    }
    if (t == 1023) off[N] = E;
}

__global__ __launch_bounds__(256) void fill_k(const int* __restrict__ ei,
                                              int* __restrict__ cursor,
                                              int* __restrict__ el_src,
                                              int* __restrict__ pose, int E) {
    int e = blockIdx.x * 256 + threadIdx.x;
    if (e >= E) return;
    int dst = ei[E + e];
    int pos = atomicAdd(&cursor[dst], 1);
    el_src[pos] = ei[e];
    pose[e] = pos;
}

// ---------------- encoders ----------------
__global__ __launch_bounds__(256) void node_enc_k(
    const float* __restrict__ x, const float* __restrict__ w,
    const float* __restrict__ b, float* __restrict__ h,
    bf16* __restrict__ h_bf, int N) {
    int t = blockIdx.x * 256 + threadIdx.x;
    if (t >= N * 128) return;
    int n = t >> 7, d = t & 127;
    float acc = b[d];
#pragma unroll
    for (int i = 0; i < 9; ++i) acc += x[n * 9 + i] * w[i * 128 + d];
    float r = fmaxf(acc, 0.f);
    h[t] = r;
    h_bf[t] = __float2bfloat16(r);
}

// writes rows permuted into CSR position order
__global__ __launch_bounds__(256) void edge_enc_k(
    const float* __restrict__ ea, const float* __restrict__ w,
    const float* __restrict__ b, const int* __restrict__ pose,
    bf16* __restrict__ outp, int E) {
    int t = blockIdx.x * 256 + threadIdx.x;
    if (t >= E * 128) return;
    int e = t >> 7, d = t & 127;
    float acc = b[d];
#pragma unroll
    for (int i = 0; i < 3; ++i) acc += ea[e * 3 + i] * w[i * 128 + d];
    outp[(size_t)pose[e] * 128 + d] = __float2bfloat16(acc);
}

// ---------------- MFMA GEMMs: [M,128] x [128,128] ----------------
// block = 256 thr = 4 waves; tile 64 rows; wave w owns cols [w*32, w*32+32)
__global__ __launch_bounds__(256) void qkvs_k(
    const bf16* __restrict__ A, const bf16* __restrict__ Wp,
    const float* __restrict__ bp,
    bf16* __restrict__ Q, bf16* __restrict__ K, bf16* __restrict__ V,
    float* __restrict__ S, int M) {
    int tid = threadIdx.x;
    int l = tid & 63, w = tid >> 6;
    int row0 = blockIdx.x * 64;
    const short* Ab = (const short*)A + (size_t)(row0 + (l & 15)) * 128 + ((l >> 4) * 8);
    short8 a[4][4];
#pragma unroll
    for (int mb = 0; mb < 4; ++mb)
#pragma unroll
        for (int kb = 0; kb < 4; ++kb)
            a[mb][kb] = *(const short8*)(Ab + mb * 16 * 128 + kb * 32);
    int colb = w * 32 + (l & 15);
#pragma unroll
    for (int s = 0; s < 4; ++s) {
        const short* Wb = (const short*)Wp + s * 16384;
        short8 bfr[2][4];
#pragma unroll
        for (int nbi = 0; nbi < 2; ++nbi)
#pragma unroll
            for (int kb = 0; kb < 4; ++kb)
                bfr[nbi][kb] = *(const short8*)(Wb + (size_t)(((w * 2 + nbi) * 4 + kb) * 64 + l) * 8);
        f32x4 acc[4][2] = {};
#pragma unroll
        for (int kb = 0; kb < 4; ++kb)
#pragma unroll
            for (int mb = 0; mb < 4; ++mb)
#pragma unroll
                for (int nbi = 0; nbi < 2; ++nbi)
                    acc[mb][nbi] = __builtin_amdgcn_mfma_f32_16x16x32_bf16(
                        a[mb][kb], bfr[nbi][kb], acc[mb][nbi], 0, 0, 0);
        float bias0 = bp[s * 128 + colb];
        float bias1 = bp[s * 128 + colb + 16];
#pragma unroll
        for (int mb = 0; mb < 4; ++mb) {
            int rbase = row0 + mb * 16 + (l >> 4) * 4;
#pragma unroll
            for (int j = 0; j < 4; ++j) {
                int r = rbase + j;
                if (r >= M) continue;
#pragma unroll
                for (int nbi = 0; nbi < 2; ++nbi) {
                    int c = colb + nbi * 16;
                    float v = acc[mb][nbi][j] + (nbi ? bias1 : bias0);
                    if (s == 0) Q[(size_t)r * 128 + c] = __float2bfloat16(v);
                    else if (s == 1) K[(size_t)r * 128 + c] = __float2bfloat16(v);
                    else if (s == 2) V[(size_t)r * 128 + c] = __float2bfloat16(v);
                    else S[(size_t)r * 128 + c] = v;
                }
            }
        }
    }
}

__global__ __launch_bounds__(256) void egemm_k(
    const bf16* __restrict__ A, const bf16* __restrict__ Wp,
    bf16* __restrict__ O, int M) {
    int tid = threadIdx.x;
    int l = tid & 63, w = tid >> 6;
    int row0 = blockIdx.x * 64;
    const short* Ab = (const short*)A + (size_t)(row0 + (l & 15)) * 128 + ((l >> 4) * 8);
    short8 a[4][4];
#pragma unroll
    for (int mb = 0; mb < 4; ++mb)
#pragma unroll
        for (int kb = 0; kb < 4; ++kb)
            a[mb][kb] = *(const short8*)(Ab + mb * 16 * 128 + kb * 32);
    short8 bfr[2][4];
#pragma unroll
    for (int nbi = 0; nbi < 2; ++nbi)
#pragma unroll
        for (int kb = 0; kb < 4; ++kb)
            bfr[nbi][kb] = *(const short8*)((const short*)Wp + (size_t)(((w * 2 + nbi) * 4 + kb) * 64 + l) * 8);
    f32x4 acc[4][2] = {};
#pragma unroll
    for (int kb = 0; kb < 4; ++kb)
#pragma unroll
        for (int mb = 0; mb < 4; ++mb)
#pragma unroll
            for (int nbi = 0; nbi < 2; ++nbi)
                acc[mb][nbi] = __builtin_amdgcn_mfma_f32_16x16x32_bf16(
                    a[mb][kb], bfr[nbi][kb], acc[mb][nbi], 0, 0, 0);
    int colb = w * 32 + (l & 15);
#pragma unroll
    for (int mb = 0; mb < 4; ++mb) {
        int rbase = row0 + mb * 16 + (l >> 4) * 4;
#pragma unroll
        for (int j = 0; j < 4; ++j) {
            int r = rbase + j;
            if (r >= M) continue;
#pragma unroll
            for (int nbi = 0; nbi < 2; ++nbi)
                O[(size_t)r * 128 + colb + nbi * 16] = __float2bfloat16(acc[mb][nbi][j]);
        }
    }
}

// ---------------- fused attention: one wave per destination node ----------------
// exp without max-subtraction (identical after normalization); no atomics.
__global__ __launch_bounds__(256) void attn_k(
    const int* __restrict__ off, const int* __restrict__ el_src,
    const bf16* __restrict__ Q, const bf16* __restrict__ K,
    const bf16* __restrict__ V, const bf16* __restrict__ Ebuf,
    float* __restrict__ agg, int N) {
    int gw = (blockIdx.x * 256 + threadIdx.x) >> 6;
    int l = threadIdx.x & 63;
    int nw = (gridDim.x * 256) >> 6;
    const unsigned* Q2 = (const unsigned*)Q;
    const unsigned* K2 = (const unsigned*)K;
    const unsigned* V2 = (const unsigned*)V;
    const unsigned* E2 = (const unsigned*)Ebuf;
    for (int n = gw; n < N; n += nw) {
        unsigned q2 = Q2[(size_t)n * 64 + l];
        float q0 = blo(q2), q1 = bhi(q2);
        float acc0 = 0.f, acc1 = 0.f, den = 0.f;
        int i0 = off[n], i1 = off[n + 1];
        for (int i = i0; i < i1; ++i) {
            int src = el_src[i];
            unsigned k2 = K2[(size_t)src * 64 + l];
            unsigned v2 = V2[(size_t)src * 64 + l];
            unsigned e2 = E2[(size_t)i * 64 + l];
            float e0 = blo(e2), e1 = bhi(e2);
            float s = q0 * (blo(k2) + e0) + q1 * (bhi(k2) + e1);
            s += __shfl_xor(s, 1);
            s += __shfl_xor(s, 2);
            s += __shfl_xor(s, 4);
            float p = __expf(s * 0.25f);
            den += p;
            acc0 += (blo(v2) + e0) * p;
            acc1 += (bhi(v2) + e1) * p;
        }
        float inv = den > 0.f ? 1.f / den : 0.f;
        agg[(size_t)n * 128 + 2 * l]     = acc0 * inv;
        agg[(size_t)n * 128 + 2 * l + 1] = acc1 * inv;
    }
}

// ---------------- beta gate + residual + layernorm ----------------
__global__ __launch_bounds__(64) void combine_k(
    const float* __restrict__ agg, const float* __restrict__ S,
    float* __restrict__ h, bf16* __restrict__ h_bf,
    const float* __restrict__ Wb, const float* __restrict__ lng,
    const float* __restrict__ lnb, int N) {
    int n = blockIdx.x;
    int t = threadIdx.x;
    int d0 = t, d1 = t + 64;
    size_t base = (size_t)n * 128;
    float o0 = agg[base + d0], o1 = agg[base + d1];
    float s0 = S[base + d0], s1 = S[base + d1];
    float part = o0 * Wb[d0] + s0 * Wb[128 + d0] + (o0 - s0) * Wb[256 + d0]
               + o1 * Wb[d1] + s1 * Wb[128 + d1] + (o1 - s1) * Wb[256 + d1];
    float g = waveReduceSum(part);
    float beta = 1.f / (1.f + __expf(-g));
    float y0 = beta * s0 + (1.f - beta) * o0;
    float y1 = beta * s1 + (1.f - beta) * o1;
    float z0 = y0 + h[base + d0];
    float z1 = y1 + h[base + d1];
    float mean = waveReduceSum(z0 + z1) * (1.f / 128.f);
    float c0 = z0 - mean, c1 = z1 - mean;
    float var = waveReduceSum(c0 * c0 + c1 * c1) * (1.f / 128.f);
    float inv = rsqrtf(var + 1e-5f);
    float r0 = c0 * inv * lng[d0] + lnb[d0];
    float r1 = c1 * inv * lng[d1] + lnb[d1];
    h[base + d0] = r0;
    h[base + d1] = r1;
    h_bf[base + d0] = __float2bfloat16(r0);
    h_bf[base + d1] = __float2bfloat16(r1);
}

// ---------------- pooling + head ----------------
__global__ __launch_bounds__(256) void pool_sum_k(
    const float* __restrict__ h, const int* __restrict__ batch,
    float* __restrict__ psum, int N) {
    int t = blockIdx.x * 256 + threadIdx.x;
    if (t >= N * 128) return;
    int n = t >> 7, d = t & 127;
    atomicAdd(&psum[batch[n] * 128 + d], h[t]);
}

__global__ __launch_bounds__(256) void pool_cnt_k(
    const int* __restrict__ batch, float* __restrict__ pcnt, int N) {
    int t = blockIdx.x * 256 + threadIdx.x;
    if (t >= N) return;
    atomicAdd(&pcnt[batch[t]], 1.f);
}

__global__ __launch_bounds__(64) void head_k(
    const float* __restrict__ psum, const float* __restrict__ pcnt,
    const float* __restrict__ h1w, const float* __restrict__ h1b,
    const float* __restrict__ h2w, const float* __restrict__ h2b,
    float* __restrict__ out) {
    __shared__ float pl[128];
    __shared__ float hid[64];
    int g = blockIdx.x;
    int t = threadIdx.x;
    float cnt = fmaxf(pcnt[g], 1.f);
    for (int i = t; i < 128; i += 64) pl[i] = psum[g * 128 + i] / cnt;
    __syncthreads();
    float a = h1b[t];
    for (int k = 0; k < 128; ++k) a += pl[k] * h1w[k * 64 + t];
    hid[t] = fmaxf(a, 0.f);
    __syncthreads();
    if (t < 10) {
        float o = h2b[t];
        for (int k = 0; k < 64; ++k) o += hid[k] * h2w[k * 10 + t];
        out[g * 10 + t] = o;
    }
}

extern "C" void kernel_launch(void* const* d_in, const int* in_sizes, int n_in,
                              void* d_out, int out_size, void* d_ws, size_t ws_size,
                              hipStream_t stream) {
    const float* x      = (const float*)d_in[0];
    const int*   ei     = (const int*)d_in[1];
    const float* eattr  = (const float*)d_in[2];
    const int*   batch  = (const int*)d_in[3];
    const float* node_w = (const float*)d_in[4];
    const float* node_b = (const float*)d_in[5];
    const float* edge_w = (const float*)d_in[6];
    const float* edge_b = (const float*)d_in[7];
    const float* Wq     = (const float*)d_in[8];
    const float* bq     = (const float*)d_in[9];
    const float* Wk     = (const float*)d_in[10];
    const float* bk     = (const float*)d_in[11];
    const float* Wv     = (const float*)d_in[12];
    const float* bv     = (const float*)d_in[13];
    const float* We     = (const float*)d_in[14];
    const float* Wskip  = (const float*)d_in[15];
    const float* bskip  = (const float*)d_in[16];
    const float* Wbeta  = (const float*)d_in[17];
    const float* ln_g   = (const float*)d_in[18];
    const float* ln_b   = (const float*)d_in[19];
    const float* h1_w   = (const float*)d_in[20];
    const float* h1_b   = (const float*)d_in[21];
    const float* h2_w   = (const float*)d_in[22];
    const float* h2_b   = (const float*)d_in[23];
    float* out = (float*)d_out;

    const int N = in_sizes[3];
    const int E = in_sizes[2] / 3;
    const int L = in_sizes[8] / 16384;
    const int G = out_size / 10;

    char* wptr = (char*)d_ws;
    auto alloc = [&](size_t bytes) {
        char* p = wptr;
        wptr += (bytes + 255) & ~(size_t)255;
        return p;
    };
    float* h      = (float*)alloc((size_t)(N + 64) * 128 * 4);
    bf16*  h_bf   = (bf16*)alloc((size_t)(N + 64) * 128 * 2);
    bf16*  Qb     = (bf16*)alloc((size_t)(N + 64) * 128 * 2);
    bf16*  Kb     = (bf16*)alloc((size_t)(N + 64) * 128 * 2);
    bf16*  Vb     = (bf16*)alloc((size_t)(N + 64) * 128 * 2);
    float* S      = (float*)alloc((size_t)(N + 64) * 128 * 4);
    float* agg    = (float*)alloc((size_t)N * 128 * 4);
    bf16*  ea_bf  = (bf16*)alloc((size_t)E * 128 * 2);
    bf16*  e_     = (bf16*)alloc((size_t)E * 128 * 2);
    bf16*  Wpack  = (bf16*)alloc((size_t)5 * L * 16384 * 2);
    float* bpack  = (float*)alloc((size_t)4 * L * 128 * 4);
    int*   deg    = (int*)alloc((size_t)N * 4);
    int*   off    = (int*)alloc((size_t)(N + 1) * 4);
    int*   cursor = (int*)alloc((size_t)N * 4);
    int*   el_src = (int*)alloc((size_t)E * 4);
    int*   pose   = (int*)alloc((size_t)E * 4);
    float* psum   = (float*)alloc((size_t)G * 128 * 4);
    float* pcnt   = (float*)alloc((size_t)G * 4);

    dim3 b256(256), b64(64);

    // one-time prep
    pack_w_k<<<(5 * L * 16384 + 255) / 256, b256, 0, stream>>>(Wq, Wk, Wv, Wskip, We, Wpack, L);
    pack_b_k<<<(4 * L * 128 + 255) / 256, b256, 0, stream>>>(bq, bk, bv, bskip, bpack, L);
    hipMemsetAsync(deg, 0, (size_t)N * 4, stream);
    hist_k<<<(E + 255) / 256, b256, 0, stream>>>(ei, deg, E);
    scan_k<<<1, 1024, 0, stream>>>(deg, off, cursor, N, E);
    fill_k<<<(E + 255) / 256, b256, 0, stream>>>(ei, cursor, el_src, pose, E);
    node_enc_k<<<(N * 128 + 255) / 256, b256, 0, stream>>>(x, node_w, node_b, h, h_bf, N);
    edge_enc_k<<<(E * 128 + 255) / 256, b256, 0, stream>>>(eattr, edge_w, edge_b, pose, ea_bf, E);

    int gN = (N + 63) / 64, gE = (E + 63) / 64;
    int gAttn = (N + 3) / 4;
    for (int l = 0; l < L; ++l) {
        qkvs_k<<<gN, b256, 0, stream>>>(h_bf, Wpack + (size_t)l * 5 * 16384, bpack + (size_t)l * 4 * 128,
                                        Qb, Kb, Vb, S, N);
        egemm_k<<<gE, b256, 0, stream>>>(ea_bf, Wpack + ((size_t)l * 5 + 4) * 16384, e_, E);
        attn_k<<<gAttn, b256, 0, stream>>>(off, el_src, Qb, Kb, Vb, e_, agg, N);
        combine_k<<<N, b64, 0, stream>>>(agg, S, h, h_bf, Wbeta + (size_t)l * 384,
                                         ln_g + (size_t)l * 128, ln_b + (size_t)l * 128, N);
    }

    hipMemsetAsync(psum, 0, (size_t)G * 128 * 4, stream);
    hipMemsetAsync(pcnt, 0, (size_t)G * 4, stream);
    pool_sum_k<<<(N * 128 + 255) / 256, b256, 0, stream>>>(h, batch, psum, N);
    pool_cnt_k<<<(N + 255) / 256, b256, 0, stream>>>(batch, pcnt, N);
    head_k<<<G, b64, 0, stream>>>(psum, pcnt, h1_w, h1_b, h2_w, h2_b, out);
}

// Round 3
// 475.286 us; speedup vs baseline: 4.6989x; 1.5880x over previous
//
#include <hip/hip_runtime.h>
#include <hip/hip_bf16.h>

typedef __hip_bfloat16 bf16;
typedef __attribute__((ext_vector_type(8))) short short8;
typedef __attribute__((ext_vector_type(4))) float f32x4;

#define DEV __device__ __forceinline__

DEV float blo(unsigned u) { return __uint_as_float(u << 16); }
DEV float bhi(unsigned u) { return __uint_as_float(u & 0xffff0000u); }

DEV float waveReduceSum(float v) {
#pragma unroll
    for (int m = 1; m < 64; m <<= 1) v += __shfl_xor(v, m);
    return v;
}

// ---------------- weight packing into MFMA B-fragment order ----------------
// B frag for 16x16x32: lane l supplies B[k][n] with k=(l>>4)*8+j (j=0..7), n=l&15,
// over kb (K/32) and nb (N/16) blocks. packed idx = ((nb*4+kb)*64+l)*8+j.
// Layout: [L][s=0..3][16384], s in {Q,K,V,Skip}
__global__ __launch_bounds__(256) void pack_w_k(
    const float* __restrict__ Wq, const float* __restrict__ Wk,
    const float* __restrict__ Wv, const float* __restrict__ Ws,
    bf16* __restrict__ outp, int L) {
    int t = blockIdx.x * 256 + threadIdx.x;
    if (t >= 4 * L * 16384) return;
    int p = t & 16383;
    int ls = t >> 14;
    int l = ls >> 2, s = ls & 3;
    int j = p & 7, ln = (p >> 3) & 63, kb = (p >> 9) & 3, nb = p >> 11;
    int k = kb * 32 + (ln >> 4) * 8 + j;
    int n = nb * 16 + (ln & 15);
    const float* W = (s == 0) ? Wq : (s == 1) ? Wk : (s == 2) ? Wv : Ws;
    outp[t] = __float2bfloat16(W[(size_t)l * 16384 + k * 128 + n]);
}

__global__ __launch_bounds__(256) void pack_b_k(
    const float* __restrict__ bq, const float* __restrict__ bk,
    const float* __restrict__ bv, const float* __restrict__ bs,
    float* __restrict__ outp, int L) {
    int t = blockIdx.x * 256 + threadIdx.x;
    if (t >= 4 * L * 128) return;
    int d = t & 127;
    int ls = t >> 7;
    int l = ls >> 2, s = ls & 3;
    const float* B = (s == 0) ? bq : (s == 1) ? bk : (s == 2) ? bv : bs;
    outp[t] = B[l * 128 + d];
}

// Me[l][j][n], j=0..2: edge_w[j,:] @ We_l ; j=3: edge_b @ We_l
__global__ __launch_bounds__(256) void edge_mats_k(
    const float* __restrict__ edge_w, const float* __restrict__ edge_b,
    const float* __restrict__ We, float* __restrict__ Me, int L) {
    int t = blockIdx.x * 256 + threadIdx.x;
    if (t >= L * 4 * 128) return;
    int n = t & 127, j = (t >> 7) & 3, l = t >> 9;
    const float* W = We + (size_t)l * 16384;
    const float* row = (j < 3) ? (edge_w + j * 128) : edge_b;
    float acc = 0.f;
    for (int d = 0; d < 128; ++d) acc += row[d] * W[d * 128 + n];
    Me[t] = acc;
}

// ---------------- CSR build ----------------
__global__ __launch_bounds__(256) void hist_k(const int* __restrict__ ei,
                                              int* __restrict__ deg, int E) {
    int e = blockIdx.x * 256 + threadIdx.x;
    if (e >= E) return;
    atomicAdd(&deg[ei[E + e]], 1);
}

__global__ __launch_bounds__(1024) void scan_k(const int* __restrict__ deg,
                                               int* __restrict__ off,
                                               int* __restrict__ cursor, int N, int E) {
    __shared__ int part[1024];
    int t = threadIdx.x;
    int chunk = (N + 1023) >> 10;
    int lo = t * chunk, hi = min(lo + chunk, N);
    int s = 0;
    for (int i = lo; i < hi; ++i) s += deg[i];
    part[t] = s;
    __syncthreads();
    for (int d = 1; d < 1024; d <<= 1) {
        int v = (t >= d) ? part[t - d] : 0;
        __syncthreads();
        part[t] += v;
        __syncthreads();
    }
    int base = (t == 0) ? 0 : part[t - 1];
    for (int i = lo; i < hi; ++i) {
        off[i] = base;
        cursor[i] = base;
        base += deg[i];
    }
    if (t == 1023) off[N] = E;
}

// scatter src id + edge_attr (padded float4) into CSR position order
__global__ __launch_bounds__(256) void fill_k(const int* __restrict__ ei,
                                              const float* __restrict__ eattr,
                                              int* __restrict__ cursor,
                                              int* __restrict__ el_src,
                                              float4* __restrict__ ea4, int E) {
    int e = blockIdx.x * 256 + threadIdx.x;
    if (e >= E) return;
    int dst = ei[E + e];
    int pos = atomicAdd(&cursor[dst], 1);
    el_src[pos] = ei[e];
    ea4[pos] = make_float4(eattr[e * 3], eattr[e * 3 + 1], eattr[e * 3 + 2], 0.f);
}

// ---------------- node encoder ----------------
__global__ __launch_bounds__(256) void node_enc_k(
    const float* __restrict__ x, const float* __restrict__ w,
    const float* __restrict__ b, float* __restrict__ h,
    bf16* __restrict__ h_bf, int N) {
    int t = blockIdx.x * 256 + threadIdx.x;
    if (t >= N * 128) return;
    int n = t >> 7, d = t & 127;
    float acc = b[d];
#pragma unroll
    for (int i = 0; i < 9; ++i) acc += x[n * 9 + i] * w[i * 128 + d];
    float r = fmaxf(acc, 0.f);
    h[t] = r;
    h_bf[t] = __float2bfloat16(r);
}

// ---------------- fused QKVS MFMA GEMM: [M,128] x [128,128] x4 ----------------
__global__ __launch_bounds__(256) void qkvs_k(
    const bf16* __restrict__ A, const bf16* __restrict__ Wp,
    const float* __restrict__ bp,
    bf16* __restrict__ Q, bf16* __restrict__ K, bf16* __restrict__ V,
    float* __restrict__ S, int M) {
    int tid = threadIdx.x;
    int l = tid & 63, w = tid >> 6;
    int row0 = blockIdx.x * 64;
    const short* Ab = (const short*)A + (size_t)(row0 + (l & 15)) * 128 + ((l >> 4) * 8);
    short8 a[4][4];
#pragma unroll
    for (int mb = 0; mb < 4; ++mb)
#pragma unroll
        for (int kb = 0; kb < 4; ++kb)
            a[mb][kb] = *(const short8*)(Ab + mb * 16 * 128 + kb * 32);
    int colb = w * 32 + (l & 15);
#pragma unroll
    for (int s = 0; s < 4; ++s) {
        const short* Wb = (const short*)Wp + s * 16384;
        short8 bfr[2][4];
#pragma unroll
        for (int nbi = 0; nbi < 2; ++nbi)
#pragma unroll
            for (int kb = 0; kb < 4; ++kb)
                bfr[nbi][kb] = *(const short8*)(Wb + (size_t)(((w * 2 + nbi) * 4 + kb) * 64 + l) * 8);
        f32x4 acc[4][2] = {};
#pragma unroll
        for (int kb = 0; kb < 4; ++kb)
#pragma unroll
            for (int mb = 0; mb < 4; ++mb)
#pragma unroll
                for (int nbi = 0; nbi < 2; ++nbi)
                    acc[mb][nbi] = __builtin_amdgcn_mfma_f32_16x16x32_bf16(
                        a[mb][kb], bfr[nbi][kb], acc[mb][nbi], 0, 0, 0);
        float bias0 = bp[s * 128 + colb];
        float bias1 = bp[s * 128 + colb + 16];
#pragma unroll
        for (int mb = 0; mb < 4; ++mb) {
            int rbase = row0 + mb * 16 + (l >> 4) * 4;
#pragma unroll
            for (int j = 0; j < 4; ++j) {
                int r = rbase + j;
                if (r >= M) continue;
#pragma unroll
                for (int nbi = 0; nbi < 2; ++nbi) {
                    int c = colb + nbi * 16;
                    float v = acc[mb][nbi][j] + (nbi ? bias1 : bias0);
                    if (s == 0) Q[(size_t)r * 128 + c] = __float2bfloat16(v);
                    else if (s == 1) K[(size_t)r * 128 + c] = __float2bfloat16(v);
                    else if (s == 2) V[(size_t)r * 128 + c] = __float2bfloat16(v);
                    else S[(size_t)r * 128 + c] = v;
                }
            }
        }
    }
}

// ---------------- fused attention + beta gate + residual + layernorm ----------------
// one wave per destination node; e computed on the fly (rank-3); no atomics.
__global__ __launch_bounds__(256) void attn_k(
    const int* __restrict__ off, const int* __restrict__ el_src,
    const float4* __restrict__ ea4, const float* __restrict__ Me,
    const bf16* __restrict__ Q, const bf16* __restrict__ K,
    const bf16* __restrict__ V, const float* __restrict__ S,
    float* __restrict__ h, bf16* __restrict__ h_bf,
    const float* __restrict__ Wb, const float* __restrict__ lng,
    const float* __restrict__ lnb, int N) {
    int gw = (blockIdx.x * 256 + threadIdx.x) >> 6;
    int l = threadIdx.x & 63;
    int nw = (gridDim.x * 256) >> 6;
    int d0 = 2 * l, d1 = 2 * l + 1;
    // per-lane constants for this layer
    float m00 = Me[d0],       m01 = Me[d1];
    float m10 = Me[128 + d0], m11 = Me[128 + d1];
    float m20 = Me[256 + d0], m21 = Me[256 + d1];
    float mb0 = Me[384 + d0], mb1 = Me[384 + d1];
    float wba0 = Wb[d0],       wba1 = Wb[d1];
    float wbb0 = Wb[128 + d0], wbb1 = Wb[128 + d1];
    float wbc0 = Wb[256 + d0], wbc1 = Wb[256 + d1];
    float g0 = lng[d0], g1 = lng[d1];
    float bb0 = lnb[d0], bb1 = lnb[d1];
    const unsigned* Q2 = (const unsigned*)Q;
    const unsigned* K2 = (const unsigned*)K;
    const unsigned* V2 = (const unsigned*)V;
    for (int n = gw; n < N; n += nw) {
        unsigned q2 = Q2[(size_t)n * 64 + l];
        float q0 = blo(q2), q1 = bhi(q2);
        float acc0 = 0.f, acc1 = 0.f, den = 0.f;
        int i0 = off[n], i1 = off[n + 1];
        for (int i = i0; i < i1; ++i) {
            int src = el_src[i];
            float4 aeb = ea4[i];
            unsigned k2 = K2[(size_t)src * 64 + l];
            unsigned v2 = V2[(size_t)src * 64 + l];
            float e0 = fmaf(aeb.x, m00, fmaf(aeb.y, m10, fmaf(aeb.z, m20, mb0)));
            float e1 = fmaf(aeb.x, m01, fmaf(aeb.y, m11, fmaf(aeb.z, m21, mb1)));
            float s = q0 * (blo(k2) + e0) + q1 * (bhi(k2) + e1);
            s += __shfl_xor(s, 1);
            s += __shfl_xor(s, 2);
            s += __shfl_xor(s, 4);
            float p = __expf(s * 0.25f);
            den += p;
            acc0 += (blo(v2) + e0) * p;
            acc1 += (bhi(v2) + e1) * p;
        }
        float inv = den > 0.f ? 1.f / den : 0.f;
        float o0 = acc0 * inv, o1 = acc1 * inv;
        size_t base = (size_t)n * 128;
        float s0 = S[base + d0], s1 = S[base + d1];
        float part = o0 * wba0 + s0 * wbb0 + (o0 - s0) * wbc0
                   + o1 * wba1 + s1 * wbb1 + (o1 - s1) * wbc1;
        float g = waveReduceSum(part);
        float beta = 1.f / (1.f + __expf(-g));
        float y0 = beta * s0 + (1.f - beta) * o0;
        float y1 = beta * s1 + (1.f - beta) * o1;
        float z0 = y0 + h[base + d0];
        float z1 = y1 + h[base + d1];
        float mean = waveReduceSum(z0 + z1) * (1.f / 128.f);
        float c0 = z0 - mean, c1 = z1 - mean;
        float var = waveReduceSum(c0 * c0 + c1 * c1) * (1.f / 128.f);
        float invs = rsqrtf(var + 1e-5f);
        float r0 = c0 * invs * g0 + bb0;
        float r1 = c1 * invs * g1 + bb1;
        h[base + d0] = r0;
        h[base + d1] = r1;
        h_bf[base + d0] = __float2bfloat16(r0);
        h_bf[base + d1] = __float2bfloat16(r1);
    }
}

// ---------------- pooling + head ----------------
__global__ __launch_bounds__(256) void pool_sum_k(
    const float* __restrict__ h, const int* __restrict__ batch,
    float* __restrict__ psum, int N) {
    int t = blockIdx.x * 256 + threadIdx.x;
    if (t >= N * 128) return;
    int n = t >> 7, d = t & 127;
    atomicAdd(&psum[batch[n] * 128 + d], h[t]);
}

__global__ __launch_bounds__(256) void pool_cnt_k(
    const int* __restrict__ batch, float* __restrict__ pcnt, int N) {
    int t = blockIdx.x * 256 + threadIdx.x;
    if (t >= N) return;
    atomicAdd(&pcnt[batch[t]], 1.f);
}

__global__ __launch_bounds__(64) void head_k(
    const float* __restrict__ psum, const float* __restrict__ pcnt,
    const float* __restrict__ h1w, const float* __restrict__ h1b,
    const float* __restrict__ h2w, const float* __restrict__ h2b,
    float* __restrict__ out) {
    __shared__ float pl[128];
    __shared__ float hid[64];
    int g = blockIdx.x;
    int t = threadIdx.x;
    float cnt = fmaxf(pcnt[g], 1.f);
    for (int i = t; i < 128; i += 64) pl[i] = psum[g * 128 + i] / cnt;
    __syncthreads();
    float a = h1b[t];
    for (int k = 0; k < 128; ++k) a += pl[k] * h1w[k * 64 + t];
    hid[t] = fmaxf(a, 0.f);
    __syncthreads();
    if (t < 10) {
        float o = h2b[t];
        for (int k = 0; k < 64; ++k) o += hid[k] * h2w[k * 10 + t];
        out[g * 10 + t] = o;
    }
}

extern "C" void kernel_launch(void* const* d_in, const int* in_sizes, int n_in,
                              void* d_out, int out_size, void* d_ws, size_t ws_size,
                              hipStream_t stream) {
    const float* x      = (const float*)d_in[0];
    const int*   ei     = (const int*)d_in[1];
    const float* eattr  = (const float*)d_in[2];
    const int*   batch  = (const int*)d_in[3];
    const float* node_w = (const float*)d_in[4];
    const float* node_b = (const float*)d_in[5];
    const float* edge_w = (const float*)d_in[6];
    const float* edge_b = (const float*)d_in[7];
    const float* Wq     = (const float*)d_in[8];
    const float* bq     = (const float*)d_in[9];
    const float* Wk     = (const float*)d_in[10];
    const float* bk     = (const float*)d_in[11];
    const float* Wv     = (const float*)d_in[12];
    const float* bv     = (const float*)d_in[13];
    const float* We     = (const float*)d_in[14];
    const float* Wskip  = (const float*)d_in[15];
    const float* bskip  = (const float*)d_in[16];
    const float* Wbeta  = (const float*)d_in[17];
    const float* ln_g   = (const float*)d_in[18];
    const float* ln_b   = (const float*)d_in[19];
    const float* h1_w   = (const float*)d_in[20];
    const float* h1_b   = (const float*)d_in[21];
    const float* h2_w   = (const float*)d_in[22];
    const float* h2_b   = (const float*)d_in[23];
    float* out = (float*)d_out;

    const int N = in_sizes[3];
    const int E = in_sizes[2] / 3;
    const int L = in_sizes[8] / 16384;
    const int G = out_size / 10;

    char* wptr = (char*)d_ws;
    auto alloc = [&](size_t bytes) {
        char* p = wptr;
        wptr += (bytes + 255) & ~(size_t)255;
        return p;
    };
    float* h      = (float*)alloc((size_t)(N + 64) * 128 * 4);
    bf16*  h_bf   = (bf16*)alloc((size_t)(N + 64) * 128 * 2);
    bf16*  Qb     = (bf16*)alloc((size_t)(N + 64) * 128 * 2);
    bf16*  Kb     = (bf16*)alloc((size_t)(N + 64) * 128 * 2);
    bf16*  Vb     = (bf16*)alloc((size_t)(N + 64) * 128 * 2);
    float* S      = (float*)alloc((size_t)(N + 64) * 128 * 4);
    float4* ea4   = (float4*)alloc((size_t)E * 16);
    bf16*  Wpack  = (bf16*)alloc((size_t)4 * L * 16384 * 2);
    float* bpack  = (float*)alloc((size_t)4 * L * 128 * 4);
    float* Me     = (float*)alloc((size_t)L * 4 * 128 * 4);
    int*   deg    = (int*)alloc((size_t)N * 4);
    int*   off    = (int*)alloc((size_t)(N + 1) * 4);
    int*   cursor = (int*)alloc((size_t)N * 4);
    int*   el_src = (int*)alloc((size_t)E * 4);
    float* psum   = (float*)alloc((size_t)G * 128 * 4);
    float* pcnt   = (float*)alloc((size_t)G * 4);

    dim3 b256(256), b64(64);

    // one-time prep
    pack_w_k<<<(4 * L * 16384 + 255) / 256, b256, 0, stream>>>(Wq, Wk, Wv, Wskip, Wpack, L);
    pack_b_k<<<(4 * L * 128 + 255) / 256, b256, 0, stream>>>(bq, bk, bv, bskip, bpack, L);
    edge_mats_k<<<(L * 4 * 128 + 255) / 256, b256, 0, stream>>>(edge_w, edge_b, We, Me, L);
    hipMemsetAsync(deg, 0, (size_t)N * 4, stream);
    hist_k<<<(E + 255) / 256, b256, 0, stream>>>(ei, deg, E);
    scan_k<<<1, 1024, 0, stream>>>(deg, off, cursor, N, E);
    fill_k<<<(E + 255) / 256, b256, 0, stream>>>(ei, eattr, cursor, el_src, ea4, E);
    node_enc_k<<<(N * 128 + 255) / 256, b256, 0, stream>>>(x, node_w, node_b, h, h_bf, N);

    int gN = (N + 63) / 64;
    int gAttn = (N + 3) / 4;
    for (int l = 0; l < L; ++l) {
        qkvs_k<<<gN, b256, 0, stream>>>(h_bf, Wpack + (size_t)l * 4 * 16384,
                                        bpack + (size_t)l * 4 * 128, Qb, Kb, Vb, S, N);
        attn_k<<<gAttn, b256, 0, stream>>>(off, el_src, ea4, Me + (size_t)l * 512,
                                           Qb, Kb, Vb, S, h, h_bf,
                                           Wbeta + (size_t)l * 384,
                                           ln_g + (size_t)l * 128, ln_b + (size_t)l * 128, N);
    }

    hipMemsetAsync(psum, 0, (size_t)G * 128 * 4, stream);
    hipMemsetAsync(pcnt, 0, (size_t)G * 4, stream);
    pool_sum_k<<<(N * 128 + 255) / 256, b256, 0, stream>>>(h, batch, psum, N);
    pool_cnt_k<<<(N + 255) / 256, b256, 0, stream>>>(batch, pcnt, N);
    head_k<<<G, b64, 0, stream>>>(psum, pcnt, h1_w, h1_b, h2_w, h2_b, out);
}

// Round 4
// 400.102 us; speedup vs baseline: 5.5819x; 1.1879x over previous
//
#include <hip/hip_runtime.h>
#include <hip/hip_bf16.h>

typedef __hip_bfloat16 bf16;
typedef __attribute__((ext_vector_type(8))) short short8;
typedef __attribute__((ext_vector_type(4))) float f32x4;

#define DEV __device__ __forceinline__

DEV float blo(unsigned u) { return __uint_as_float(u << 16); }
DEV float bhi(unsigned u) { return __uint_as_float(u & 0xffff0000u); }

DEV float waveReduceSum(float v) {
#pragma unroll
    for (int m = 1; m < 64; m <<= 1) v += __shfl_xor(v, m);
    return v;
}

// ---------------- weight packing into MFMA B-fragment order ----------------
// B frag for 16x16x32: lane l supplies B[k][n] with k=(l>>4)*8+j (j=0..7), n=l&15.
// Layout: [L][s=0..3][16384], s in {Q,K,V,Skip}
__global__ __launch_bounds__(256) void pack_w_k(
    const float* __restrict__ Wq, const float* __restrict__ Wk,
    const float* __restrict__ Wv, const float* __restrict__ Ws,
    bf16* __restrict__ outp, int L) {
    int t = blockIdx.x * 256 + threadIdx.x;
    if (t >= 4 * L * 16384) return;
    int p = t & 16383;
    int ls = t >> 14;
    int l = ls >> 2, s = ls & 3;
    int j = p & 7, ln = (p >> 3) & 63, kb = (p >> 9) & 3, nb = p >> 11;
    int k = kb * 32 + (ln >> 4) * 8 + j;
    int n = nb * 16 + (ln & 15);
    const float* W = (s == 0) ? Wq : (s == 1) ? Wk : (s == 2) ? Wv : Ws;
    outp[t] = __float2bfloat16(W[(size_t)l * 16384 + k * 128 + n]);
}

__global__ __launch_bounds__(256) void pack_b_k(
    const float* __restrict__ bq, const float* __restrict__ bk,
    const float* __restrict__ bv, const float* __restrict__ bs,
    float* __restrict__ outp, int L) {
    int t = blockIdx.x * 256 + threadIdx.x;
    if (t >= 4 * L * 128) return;
    int d = t & 127;
    int ls = t >> 7;
    int l = ls >> 2, s = ls & 3;
    const float* B = (s == 0) ? bq : (s == 1) ? bk : (s == 2) ? bv : bs;
    outp[t] = B[l * 128 + d];
}

// Me[l][j][n], j=0..2: edge_w[j,:] @ We_l ; j=3: edge_b @ We_l
__global__ __launch_bounds__(256) void edge_mats_k(
    const float* __restrict__ edge_w, const float* __restrict__ edge_b,
    const float* __restrict__ We, float* __restrict__ Me, int L) {
    int t = blockIdx.x * 256 + threadIdx.x;
    if (t >= L * 4 * 128) return;
    int n = t & 127, j = (t >> 7) & 3, l = t >> 9;
    const float* W = We + (size_t)l * 16384;
    const float* row = (j < 3) ? (edge_w + j * 128) : edge_b;
    float acc = 0.f;
    for (int d = 0; d < 128; ++d) acc += row[d] * W[d * 128 + n];
    Me[t] = acc;
}

// ---------------- CSR build ----------------
__global__ __launch_bounds__(256) void hist_k(const int* __restrict__ ei,
                                              int* __restrict__ deg, int E) {
    int e = blockIdx.x * 256 + threadIdx.x;
    if (e >= E) return;
    atomicAdd(&deg[ei[E + e]], 1);
}

__global__ __launch_bounds__(1024) void scan_k(const int* __restrict__ deg,
                                               int* __restrict__ off,
                                               int* __restrict__ cursor, int N, int E) {
    __shared__ int part[1024];
    int t = threadIdx.x;
    int chunk = (N + 1023) >> 10;
    int lo = t * chunk, hi = min(lo + chunk, N);
    int s = 0;
    for (int i = lo; i < hi; ++i) s += deg[i];
    part[t] = s;
    __syncthreads();
    for (int d = 1; d < 1024; d <<= 1) {
        int v = (t >= d) ? part[t - d] : 0;
        __syncthreads();
        part[t] += v;
        __syncthreads();
    }
    int base = (t == 0) ? 0 : part[t - 1];
    for (int i = lo; i < hi; ++i) {
        off[i] = base;
        cursor[i] = base;
        base += deg[i];
    }
    if (t == 1023) off[N] = E;
}

// scatter src id + edge_attr (padded float4) into CSR position order
__global__ __launch_bounds__(256) void fill_k(const int* __restrict__ ei,
                                              const float* __restrict__ eattr,
                                              int* __restrict__ cursor,
                                              int* __restrict__ el_src,
                                              float4* __restrict__ ea4, int E) {
    int e = blockIdx.x * 256 + threadIdx.x;
    if (e >= E) return;
    int dst = ei[E + e];
    int pos = atomicAdd(&cursor[dst], 1);
    el_src[pos] = ei[e];
    ea4[pos] = make_float4(eattr[e * 3], eattr[e * 3 + 1], eattr[e * 3 + 2], 0.f);
}

// ---------------- node encoder ----------------
__global__ __launch_bounds__(256) void node_enc_k(
    const float* __restrict__ x, const float* __restrict__ w,
    const float* __restrict__ b, float* __restrict__ h,
    bf16* __restrict__ h_bf, int N) {
    int t = blockIdx.x * 256 + threadIdx.x;
    if (t >= N * 128) return;
    int n = t >> 7, d = t & 127;
    float acc = b[d];
#pragma unroll
    for (int i = 0; i < 9; ++i) acc += x[n * 9 + i] * w[i * 128 + d];
    float r = fmaxf(acc, 0.f);
    h[t] = r;
    h_bf[t] = __float2bfloat16(r);
}

// ---------------- fused QKVS MFMA GEMM: [M,128] x [128,128] x4 ----------------
// Q -> Q buffer [n][128] bf16; K,V -> interleaved kv [n][64] uint2 {Kword,Vword};
// S -> f32 [n][128]
__global__ __launch_bounds__(256) void qkvs_k(
    const bf16* __restrict__ A, const bf16* __restrict__ Wp,
    const float* __restrict__ bp,
    bf16* __restrict__ Q, bf16* __restrict__ kvb,
    float* __restrict__ S, int M) {
    int tid = threadIdx.x;
    int l = tid & 63, w = tid >> 6;
    int row0 = blockIdx.x * 64;
    const short* Ab = (const short*)A + (size_t)(row0 + (l & 15)) * 128 + ((l >> 4) * 8);
    short8 a[4][4];
#pragma unroll
    for (int mb = 0; mb < 4; ++mb)
#pragma unroll
        for (int kb = 0; kb < 4; ++kb)
            a[mb][kb] = *(const short8*)(Ab + mb * 16 * 128 + kb * 32);
    int colb = w * 32 + (l & 15);
#pragma unroll
    for (int s = 0; s < 4; ++s) {
        const short* Wb = (const short*)Wp + s * 16384;
        short8 bfr[2][4];
#pragma unroll
        for (int nbi = 0; nbi < 2; ++nbi)
#pragma unroll
            for (int kb = 0; kb < 4; ++kb)
                bfr[nbi][kb] = *(const short8*)(Wb + (size_t)(((w * 2 + nbi) * 4 + kb) * 64 + l) * 8);
        f32x4 acc[4][2] = {};
#pragma unroll
        for (int kb = 0; kb < 4; ++kb)
#pragma unroll
            for (int mb = 0; mb < 4; ++mb)
#pragma unroll
                for (int nbi = 0; nbi < 2; ++nbi)
                    acc[mb][nbi] = __builtin_amdgcn_mfma_f32_16x16x32_bf16(
                        a[mb][kb], bfr[nbi][kb], acc[mb][nbi], 0, 0, 0);
        float bias0 = bp[s * 128 + colb];
        float bias1 = bp[s * 128 + colb + 16];
#pragma unroll
        for (int mb = 0; mb < 4; ++mb) {
            int rbase = row0 + mb * 16 + (l >> 4) * 4;
#pragma unroll
            for (int j = 0; j < 4; ++j) {
                int r = rbase + j;
                if (r >= M) continue;
#pragma unroll
                for (int nbi = 0; nbi < 2; ++nbi) {
                    int c = colb + nbi * 16;
                    float v = acc[mb][nbi][j] + (nbi ? bias1 : bias0);
                    if (s == 0) {
                        Q[(size_t)r * 128 + c] = __float2bfloat16(v);
                    } else if (s == 3) {
                        S[(size_t)r * 128 + c] = v;
                    } else {
                        // kv bf16 index: ((r*64 + c/2)*4) + (c&1) + (V?2:0)
                        size_t idx = ((size_t)r * 64 + (c >> 1)) * 4 + (c & 1) + ((s == 2) ? 2 : 0);
                        kvb[idx] = __float2bfloat16(v);
                    }
                }
            }
        }
    }
}

// ---------------- fused attention + beta gate + residual + layernorm ----------------
// one wave per destination node; e computed on the fly (rank-3); no atomics.
__global__ __launch_bounds__(256) void attn_k(
    const int* __restrict__ off, const int* __restrict__ el_src,
    const float4* __restrict__ ea4, const float* __restrict__ Me,
    const bf16* __restrict__ Q, const bf16* __restrict__ kvb,
    const float* __restrict__ S,
    float* __restrict__ h, bf16* __restrict__ h_bf,
    const float* __restrict__ Wb, const float* __restrict__ lng,
    const float* __restrict__ lnb, int N) {
    int gw = (blockIdx.x * 256 + threadIdx.x) >> 6;
    int l = threadIdx.x & 63;
    int nw = (gridDim.x * 256) >> 6;
    int d0 = 2 * l, d1 = 2 * l + 1;
    // per-lane constants for this layer
    float m00 = Me[d0],       m01 = Me[d1];
    float m10 = Me[128 + d0], m11 = Me[128 + d1];
    float m20 = Me[256 + d0], m21 = Me[256 + d1];
    float mb0 = Me[384 + d0], mb1 = Me[384 + d1];
    float wba0 = Wb[d0],       wba1 = Wb[d1];
    float wbb0 = Wb[128 + d0], wbb1 = Wb[128 + d1];
    float wbc0 = Wb[256 + d0], wbc1 = Wb[256 + d1];
    float g0 = lng[d0], g1 = lng[d1];
    float bb0 = lnb[d0], bb1 = lnb[d1];
    const unsigned* Q2 = (const unsigned*)Q;
    const uint2* KV2 = (const uint2*)kvb;
    for (int n = gw; n < N; n += nw) {
        unsigned q2 = Q2[(size_t)n * 64 + l];
        float q0 = blo(q2) * 0.25f, q1 = bhi(q2) * 0.25f;  // fold 1/sqrt(C)
        float acc0 = 0.f, acc1 = 0.f, den = 0.f;
        int i0 = off[n], i1 = off[n + 1];
        int src_n = (i0 < i1) ? el_src[i0] : 0;
        float4 ae_n = (i0 < i1) ? ea4[i0] : make_float4(0, 0, 0, 0);
        for (int i = i0; i < i1; ++i) {
            int src = src_n;
            float4 aeb = ae_n;
            if (i + 1 < i1) {  // prefetch next edge scalars
                src_n = el_src[i + 1];
                ae_n = ea4[i + 1];
            }
            uint2 kv = KV2[(size_t)src * 64 + l];
            float e0 = fmaf(aeb.x, m00, fmaf(aeb.y, m10, fmaf(aeb.z, m20, mb0)));
            float e1 = fmaf(aeb.x, m01, fmaf(aeb.y, m11, fmaf(aeb.z, m21, mb1)));
            float s = q0 * (blo(kv.x) + e0) + q1 * (bhi(kv.x) + e1);
            s += __shfl_xor(s, 1);
            s += __shfl_xor(s, 2);
            s += __shfl_xor(s, 4);
            float p = __expf(s);
            den += p;
            acc0 += (blo(kv.y) + e0) * p;
            acc1 += (bhi(kv.y) + e1) * p;
        }
        float inv = den > 0.f ? 1.f / den : 0.f;
        float o0 = acc0 * inv, o1 = acc1 * inv;
        size_t base = (size_t)n * 128;
        float s0 = S[base + d0], s1 = S[base + d1];
        float part = o0 * wba0 + s0 * wbb0 + (o0 - s0) * wbc0
                   + o1 * wba1 + s1 * wbb1 + (o1 - s1) * wbc1;
        float g = waveReduceSum(part);
        float beta = 1.f / (1.f + __expf(-g));
        float y0 = beta * s0 + (1.f - beta) * o0;
        float y1 = beta * s1 + (1.f - beta) * o1;
        float z0 = y0 + h[base + d0];
        float z1 = y1 + h[base + d1];
        float mean = waveReduceSum(z0 + z1) * (1.f / 128.f);
        float c0 = z0 - mean, c1 = z1 - mean;
        float var = waveReduceSum(c0 * c0 + c1 * c1) * (1.f / 128.f);
        float invs = rsqrtf(var + 1e-5f);
        float r0 = c0 * invs * g0 + bb0;
        float r1 = c1 * invs * g1 + bb1;
        h[base + d0] = r0;
        h[base + d1] = r1;
        h_bf[base + d0] = __float2bfloat16(r0);
        h_bf[base + d1] = __float2bfloat16(r1);
    }
}

// ---------------- fused pooling + head (batch is sorted -> range per graph) ----------------
__global__ __launch_bounds__(128) void pool_head_k(
    const float* __restrict__ h, const int* __restrict__ batch,
    const float* __restrict__ h1w, const float* __restrict__ h1b,
    const float* __restrict__ h2w, const float* __restrict__ h2b,
    float* __restrict__ out, int N) {
    int g = blockIdx.x;
    int t = threadIdx.x;
    // lower_bound(batch, val): first idx with batch[idx] >= val
    auto lb = [&](int val) {
        int lo = 0, hi = N;
        while (lo < hi) {
            int mid = (lo + hi) >> 1;
            if (batch[mid] < val) lo = mid + 1; else hi = mid;
        }
        return lo;
    };
    int s = lb(g), e = lb(g + 1);
    __shared__ float pl[128];
    __shared__ float hid[64];
    float acc = 0.f;
    for (int n = s; n < e; ++n) acc += h[(size_t)n * 128 + t];
    float cnt = fmaxf((float)(e - s), 1.f);
    pl[t] = acc / cnt;
    __syncthreads();
    if (t < 64) {
        float a = h1b[t];
        for (int k = 0; k < 128; ++k) a += pl[k] * h1w[k * 64 + t];
        hid[t] = fmaxf(a, 0.f);
    }
    __syncthreads();
    if (t < 10) {
        float o = h2b[t];
        for (int k = 0; k < 64; ++k) o += hid[k] * h2w[k * 10 + t];
        out[g * 10 + t] = o;
    }
}

extern "C" void kernel_launch(void* const* d_in, const int* in_sizes, int n_in,
                              void* d_out, int out_size, void* d_ws, size_t ws_size,
                              hipStream_t stream) {
    const float* x      = (const float*)d_in[0];
    const int*   ei     = (const int*)d_in[1];
    const float* eattr  = (const float*)d_in[2];
    const int*   batch  = (const int*)d_in[3];
    const float* node_w = (const float*)d_in[4];
    const float* node_b = (const float*)d_in[5];
    const float* edge_w = (const float*)d_in[6];
    const float* edge_b = (const float*)d_in[7];
    const float* Wq     = (const float*)d_in[8];
    const float* bq     = (const float*)d_in[9];
    const float* Wk     = (const float*)d_in[10];
    const float* bk     = (const float*)d_in[11];
    const float* Wv     = (const float*)d_in[12];
    const float* bv     = (const float*)d_in[13];
    const float* We     = (const float*)d_in[14];
    const float* Wskip  = (const float*)d_in[15];
    const float* bskip  = (const float*)d_in[16];
    const float* Wbeta  = (const float*)d_in[17];
    const float* ln_g   = (const float*)d_in[18];
    const float* ln_b   = (const float*)d_in[19];
    const float* h1_w   = (const float*)d_in[20];
    const float* h1_b   = (const float*)d_in[21];
    const float* h2_w   = (const float*)d_in[22];
    const float* h2_b   = (const float*)d_in[23];
    float* out = (float*)d_out;

    const int N = in_sizes[3];
    const int E = in_sizes[2] / 3;
    const int L = in_sizes[8] / 16384;
    const int G = out_size / 10;

    char* wptr = (char*)d_ws;
    auto alloc = [&](size_t bytes) {
        char* p = wptr;
        wptr += (bytes + 255) & ~(size_t)255;
        return p;
    };
    float* h      = (float*)alloc((size_t)(N + 64) * 128 * 4);
    bf16*  h_bf   = (bf16*)alloc((size_t)(N + 64) * 128 * 2);
    bf16*  Qb     = (bf16*)alloc((size_t)(N + 64) * 128 * 2);
    bf16*  kvb    = (bf16*)alloc((size_t)(N + 64) * 256 * 2);
    float* S      = (float*)alloc((size_t)(N + 64) * 128 * 4);
    float4* ea4   = (float4*)alloc((size_t)E * 16);
    bf16*  Wpack  = (bf16*)alloc((size_t)4 * L * 16384 * 2);
    float* bpack  = (float*)alloc((size_t)4 * L * 128 * 4);
    float* Me     = (float*)alloc((size_t)L * 4 * 128 * 4);
    int*   deg    = (int*)alloc((size_t)N * 4);
    int*   off    = (int*)alloc((size_t)(N + 1) * 4);
    int*   cursor = (int*)alloc((size_t)N * 4);
    int*   el_src = (int*)alloc((size_t)E * 4);

    dim3 b256(256), b128(128);

    // one-time prep
    pack_w_k<<<(4 * L * 16384 + 255) / 256, b256, 0, stream>>>(Wq, Wk, Wv, Wskip, Wpack, L);
    pack_b_k<<<(4 * L * 128 + 255) / 256, b256, 0, stream>>>(bq, bk, bv, bskip, bpack, L);
    edge_mats_k<<<(L * 4 * 128 + 255) / 256, b256, 0, stream>>>(edge_w, edge_b, We, Me, L);
    hipMemsetAsync(deg, 0, (size_t)N * 4, stream);
    hist_k<<<(E + 255) / 256, b256, 0, stream>>>(ei, deg, E);
    scan_k<<<1, 1024, 0, stream>>>(deg, off, cursor, N, E);
    fill_k<<<(E + 255) / 256, b256, 0, stream>>>(ei, eattr, cursor, el_src, ea4, E);
    node_enc_k<<<(N * 128 + 255) / 256, b256, 0, stream>>>(x, node_w, node_b, h, h_bf, N);

    int gN = (N + 63) / 64;
    int gAttn = (N + 3) / 4;
    for (int l = 0; l < L; ++l) {
        qkvs_k<<<gN, b256, 0, stream>>>(h_bf, Wpack + (size_t)l * 4 * 16384,
                                        bpack + (size_t)l * 4 * 128, Qb, kvb, S, N);
        attn_k<<<gAttn, b256, 0, stream>>>(off, el_src, ea4, Me + (size_t)l * 512,
                                           Qb, kvb, S, h, h_bf,
                                           Wbeta + (size_t)l * 384,
                                           ln_g + (size_t)l * 128, ln_b + (size_t)l * 128, N);
    }

    pool_head_k<<<G, b128, 0, stream>>>(h, batch, h1_w, h1_b, h2_w, h2_b, out, N);
}